// Round 13
// baseline (370.389 us; speedup 1.0000x reference)
//
#include <hip/hip_runtime.h>
#include <cfloat>
#include <climits>

#define ROWS    1024
#define VOCABSZ 128000
#define NBEAMS  16
#define NBATCH  64
#define CURLEN  8
#define KTOP    16
#define WPB     4                    // waves per block (kernel 1)
#define NSTEP   125                  // 125 float4-steps x 1024 floats = 128000
#define TCAP    96                   // tuple slots per wave (float4 + base)
#define TGUARD  80                   // stop appending past this (ovf -> rescue)
#define RCAP    (4 * TCAP)           // rescue/expand per-element capacity (384)
#define RFLUSH  320                  // rescue mid-flush threshold
#define LOG2E   1.4426950408889634f
#define LN2     0.6931471805599453f
#define THRY    (3.30f * LOG2E)      // static threshold, y-domain (~62/row)

#if __has_builtin(__builtin_amdgcn_exp2f)
#define EXP2(x) __builtin_amdgcn_exp2f(x)
#else
#define EXP2(x) exp2f(x)
#endif

// ---------------------------------------------------------------------------
// Kernel 1: one block per row, 4 waves, grid 1024 (R10's winning geometry).
// HOT LOOP: plain rolled loop, NO manual prefetch registers — #pragma
// unroll 8 lets LLVM software-pipeline with counted vmcnt waits and renamed
// registers (no rotation v_movs, no iteration-boundary drain). Per step:
// 4 mul + 4 exp2 + 4 add + 3 max + 1 cmp + wave-uniform branch; passing
// lanes (~11% of steps) store one float4 tuple + base via a single ballot.
// All top-k machinery is cold code after the loop (R10 structure).
// Correctness for ANY input: wave ovf or row above-count<16 -> exact rescan.
// ---------------------------------------------------------------------------
__global__ __launch_bounds__(256) void k1_scan(const float* __restrict__ logits,
                                               float* __restrict__ wsS,
                                               float* __restrict__ wsV,
                                               int* __restrict__ wsI) {
    __shared__ float4 tup[WPB][TCAP];      // 6 KB  (aliased by rescue values)
    __shared__ int    tub[WPB][TCAP];      // 1.5 KB
    __shared__ int    rbix[WPB][RCAP];     // 6 KB  rescue indices
    __shared__ float  redS[WPB];
    __shared__ int    redC[WPB];

    const int row  = blockIdx.x;
    const int t    = threadIdx.x;          // 0..255
    const int w    = t >> 6;
    const int lane = t & 63;
    const float4* seg4 = reinterpret_cast<const float4*>(logits + (size_t)row * VOCABSZ);
    float* rbv = reinterpret_cast<float*>(&tup[w][0]);   // in-place expansion
    int*   rbi = &rbix[w][0];

    float s0 = 0.f, s1 = 0.f, s2 = 0.f, s3 = 0.f;
    float thr = THRY;
    int   cnt = 0;                   // wave-uniform tuple count
    bool  ovf = false;

#define STEP(I, P) do {                                                        \
        const float y0 = (P).x * LOG2E, y1 = (P).y * LOG2E;                    \
        const float y2 = (P).z * LOG2E, y3 = (P).w * LOG2E;                    \
        s0 += EXP2(y0); s1 += EXP2(y1); s2 += EXP2(y2); s3 += EXP2(y3);        \
        const float mx = fmaxf(fmaxf(y0, y1), fmaxf(y2, y3));                  \
        if (__any(mx > thr)) {                                                 \
            const unsigned long long mk = __ballot(mx > thr);                  \
            const int pos = cnt + __popcll(mk & ((1ull << lane) - 1ull));      \
            if (mx > thr && pos < TCAP) {                                      \
                tup[w][pos] = make_float4(y0, y1, y2, y3);                     \
                tub[w][pos] = (I) * 1024 + t * 4;                              \
            }                                                                  \
            cnt += __popcll(mk);                                               \
            if (cnt > TGUARD) { ovf = true; thr = FLT_MAX; }                   \
        }                                                                      \
    } while (0)

    // plain rolled hot loop — compiler-scheduled pipelining (unroll 8:
    // 15 x 8 + 5 epilogue; 8 independent loads in flight, no copies)
    #pragma unroll 8
    for (int i = 0; i < NSTEP; ++i) {
        const float4 X = seg4[i * 256 + t];
        STEP(i, X);
    }
#undef STEP

    // ---- cold region from here ----

    float kv = -FLT_MAX; int ki = 0;
    auto do_flush = [&](int n) {
        kv = -FLT_MAX; ki = 0;
        for (int r = 0; r < KTOP; r++) {
            float bv = -FLT_MAX; int bi = INT_MAX; int bp = -1;
            for (int e = lane; e < n; e += 64) {
                const float v  = rbv[e];
                const int   ii = rbi[e];
                if (v > bv || (v == bv && ii < bi)) { bv = v; bi = ii; bp = e; }
            }
            for (int o = 32; o > 0; o >>= 1) {
                const float ov = __shfl_xor(bv, o);
                const int   oi = __shfl_xor(bi, o);
                const int   op = __shfl_xor(bp, o);
                if (ov > bv || (ov == bv && oi < bi)) { bv = ov; bi = oi; bp = op; }
            }
            if (lane == 0 && bp >= 0) rbv[bp] = -FLT_MAX;   // consume
            if (lane == r) { kv = bv; ki = bi; }
            thr = bv;
        }
    };

    // expand tuples in place; count elems above static THRY
    const int nt = (cnt < TCAP) ? cnt : TCAP;
    int above = 0;
    for (int e = lane; e < nt; e += 64) {
        const float4 v = tup[w][e];
        const int    b = tub[w][e];
        above += (v.x > THRY) + (v.y > THRY) + (v.z > THRY) + (v.w > THRY);
        rbv[4 * e + 0] = v.x; rbi[4 * e + 0] = b + 0;
        rbv[4 * e + 1] = v.y; rbi[4 * e + 1] = b + 1;
        rbv[4 * e + 2] = v.z; rbi[4 * e + 2] = b + 2;
        rbv[4 * e + 3] = v.w; rbi[4 * e + 3] = b + 3;
    }
    for (int o = 32; o > 0; o >>= 1) above += __shfl_xor(above, o);

    // block reductions: sum + validity count
    float s = (s0 + s1) + (s2 + s3);
    for (int o = 32; o > 0; o >>= 1) s += __shfl_xor(s, o);
    if (lane == 0) { redS[w] = s; redC[w] = ovf ? -(1 << 20) : above; }
    __syncthreads();
    if (t == 0) wsS[row] = (redS[0] + redS[1]) + (redS[2] + redS[3]);
    const int blockcnt = redC[0] + redC[1] + redC[2] + redC[3];

    int cnt4 = 4 * nt;
    if (blockcnt < KTOP) {
        // cold exact rescue: rescan this wave's subset with self-raising thr
        thr = -FLT_MAX; cnt4 = 0;
        #pragma unroll 1
        for (int i = 0; i < NSTEP; ++i) {
            const float4 X = seg4[i * 256 + t];
            const float ys[4] = {X.x * LOG2E, X.y * LOG2E, X.z * LOG2E, X.w * LOG2E};
            #pragma unroll
            for (int j = 0; j < 4; ++j) {
                const bool pr = ys[j] > thr;
                const unsigned long long mk = __ballot(pr);
                if (mk) {
                    const int pos = cnt4 + __popcll(mk & ((1ull << lane) - 1ull));
                    if (pr && pos < RCAP) { rbv[pos] = ys[j]; rbi[pos] = i * 1024 + t * 4 + j; }
                    cnt4 += __popcll(mk);
                    if (cnt4 > RFLUSH) {
                        do_flush(cnt4);
                        if (lane < KTOP) { rbv[lane] = kv; rbi[lane] = ki; }
                        cnt4 = KTOP;
                    }
                }
            }
        }
    }

    do_flush(cnt4);   // final exact wave top-16 (pads -FLT_MAX if cnt4 < 16)

    // layout: 64 slots/row: row*64 + w*16 + r
    if (lane < KTOP) {
        wsV[(size_t)row * 64 + w * KTOP + lane] = kv;
        wsI[(size_t)row * 64 + w * KTOP + lane] = ki;
    }
}

// ---------------------------------------------------------------------------
// Kernel 2: one wave per batch. 16 rows x 64 candidates = 1024 candidates
// (16 per lane). Score sc = ln2*(y - log2(S)) + bs; top-16 with jax
// tie-break (score desc, flat idx rw*V+idx asc); f32 out.
// ---------------------------------------------------------------------------
__global__ __launch_bounds__(64) void k2_select(const float* __restrict__ wsS,
                                                const float* __restrict__ wsV,
                                                const int* __restrict__ wsI,
                                                const float* __restrict__ beam_scores,
                                                const int* __restrict__ dec_ids,
                                                const int* __restrict__ beam_idx_offset,
                                                float* __restrict__ out) {
    const int batch = blockIdx.x;
    const int lane  = threadIdx.x;   // 0..63

    __shared__ float LSs[NBEAMS], BSs[NBEAMS];
    if (lane < NBEAMS) {
        const int row = batch * NBEAMS + lane;
        LSs[lane] = log2f(wsS[row]);
        BSs[lane] = beam_scores[row];
    }
    __syncthreads();

    // candidate (p, lane): row p within batch, slot lane
    float sc[16]; int cb[16];
    #pragma unroll
    for (int p = 0; p < 16; p++) {
        const size_t base = (size_t)(batch * NBEAMS + p) * 64 + lane;
        const float v = wsV[base];               // y-domain (-FLT_MAX pads)
        const int idx = wsI[base];
        sc[p] = (v - LSs[p]) * LN2 + BSs[p];
        cb[p] = p * VOCABSZ + idx;
    }

    unsigned int selmask = 0;
    float fs = 0.f; int fc = 0;       // lane r keeps r-th winner
    for (int r = 0; r < KTOP; r++) {
        float bv = -FLT_MAX; int bi = INT_MAX; int bslot = -1;
        #pragma unroll
        for (int p = 0; p < 16; p++) {
            const bool avail = !((selmask >> p) & 1u);
            if (avail && (sc[p] > bv || (sc[p] == bv && cb[p] < bi))) {
                bv = sc[p]; bi = cb[p]; bslot = p;
            }
        }
        int bl = lane;
        for (int o = 32; o > 0; o >>= 1) {
            const float ov  = __shfl_xor(bv, o);
            const int   oi  = __shfl_xor(bi, o);
            const int   obl = __shfl_xor(bl, o);
            const int   obs = __shfl_xor(bslot, o);
            if (ov > bv || (ov == bv && oi < bi)) { bv = ov; bi = oi; bl = obl; bslot = obs; }
        }
        if (lane == bl) selmask |= (1u << bslot);
        if (lane == r) { fs = bv; fc = bi; }
    }

    if (lane < NBEAMS) {
        const int out_row = batch * NBEAMS + lane;
        const int beam  = fc / VOCABSZ;
        const int token = fc - beam * VOCABSZ;
        float* out0 = out;                          // (1024, 9) ids as f32
        float* out1 = out + ROWS * (CURLEN + 1);    // (1024,) scores
        out1[out_row] = fs;
        const int src = beam + beam_idx_offset[out_row];
        #pragma unroll
        for (int j = 0; j < CURLEN; j++)
            out0[out_row * (CURLEN + 1) + j] = (float)dec_ids[src * CURLEN + j];
        out0[out_row * (CURLEN + 1) + CURLEN] = (float)token;
    }
}

extern "C" void kernel_launch(void* const* d_in, const int* in_sizes, int n_in,
                              void* d_out, int out_size, void* d_ws, size_t ws_size,
                              hipStream_t stream) {
    const float* logits = (const float*)d_in[0];
    const int*   dec    = (const int*)d_in[1];
    const float* bscore = (const float*)d_in[2];
    const int*   bio    = (const int*)d_in[3];

    float* ws  = (float*)d_ws;
    float* wsS = ws;                       // 1024
    float* wsV = ws + ROWS;                // 1024*64
    int*   wsI = (int*)(ws + ROWS + ROWS * 64);

    k1_scan<<<ROWS, 256, 0, stream>>>(logits, wsS, wsV, wsI);
    k2_select<<<NBATCH, 64, 0, stream>>>(wsS, wsV, wsI, bscore, dec, bio,
                                         (float*)d_out);
}

// Round 14
// 137.181 us; speedup vs baseline: 2.7000x; 2.7000x over previous
//
#include <hip/hip_runtime.h>
#include <cfloat>
#include <climits>

#define ROWS    1024
#define VOCABSZ 128000
#define NBEAMS  16
#define NBATCH  64
#define CURLEN  8
#define KTOP    16
#define WPB     4                    // waves per block (kernel 1)
#define NSTEP   125                  // 125 float4-steps x 1024 floats = 128000
#define NB8     15                   // 15 batches of 8 steps (+5 tail)
#define TCAP    96                   // tuple slots per wave (float4 + base)
#define TGUARD  80                   // stop appending past this (ovf -> rescue)
#define RCAP    (4 * TCAP)           // rescue/expand per-element capacity (384)
#define RFLUSH  320                  // rescue mid-flush threshold
#define LOG2E   1.4426950408889634f
#define LN2     0.6931471805599453f
#define THRY    (3.30f * LOG2E)      // static threshold, y-domain (~62/row)

#if __has_builtin(__builtin_amdgcn_exp2f)
#define EXP2(x) __builtin_amdgcn_exp2f(x)
#else
#define EXP2(x) exp2f(x)
#endif

// ---------------------------------------------------------------------------
// Kernel 1: one block per row, 4 waves, grid 1024 (R10 geometry). Hot loop =
// 15 explicit batches of 8: {8 independent loads} -> {8 PURE steps: mul/exp2/
// add/max + wave-uniform flag bit, NO memory side-effects} -> {ONE deferred
// append branch using still-live X registers}. This gives the compiler a
// side-effect-free window to pipeline 8 loads with counted vmcnt (R13's goal)
// without the regalloc/spill blowup (R13's failure: VGPR=256, 68MB scratch).
// All top-k machinery is cold code after the loop (R10 structure).
// Correctness for ANY input: wave ovf or row above-count<16 -> exact rescan.
// ---------------------------------------------------------------------------
__global__ __launch_bounds__(256) void k1_scan(const float* __restrict__ logits,
                                               float* __restrict__ wsS,
                                               float* __restrict__ wsV,
                                               int* __restrict__ wsI) {
    __shared__ float4 tup[WPB][TCAP];      // 6 KB  (aliased by rescue values)
    __shared__ int    tub[WPB][TCAP];      // 1.5 KB
    __shared__ int    rbix[WPB][RCAP];     // 6 KB  rescue indices
    __shared__ float  redS[WPB];
    __shared__ int    redC[WPB];

    const int row  = blockIdx.x;
    const int t    = threadIdx.x;          // 0..255
    const int w    = t >> 6;
    const int lane = t & 63;
    const float4* seg4 = reinterpret_cast<const float4*>(logits + (size_t)row * VOCABSZ);
    float* rbv = reinterpret_cast<float*>(&tup[w][0]);   // in-place expansion
    int*   rbi = &rbix[w][0];

    float s0 = 0.f, s1 = 0.f, s2 = 0.f, s3 = 0.f;
    float thr = THRY;
    int   cnt = 0;                   // wave-uniform tuple count
    bool  ovf = false;

    // pure step: sums + flag bit only (no memory ops, branch-free data path)
#define PSTEP(K, P) do {                                                       \
        const float y0 = (P).x * LOG2E, y1 = (P).y * LOG2E;                    \
        const float y2 = (P).z * LOG2E, y3 = (P).w * LOG2E;                    \
        s0 += EXP2(y0); s1 += EXP2(y1); s2 += EXP2(y2); s3 += EXP2(y3);        \
        const float mx = fmaxf(fmaxf(y0, y1), fmaxf(y2, y3));                  \
        if (__any(mx > thr)) fl |= (1u << (K));                                \
    } while (0)

    // deferred append for flagged step (uses live X register; recompute y)
#define ASTEP(K, P, S) if ((fl >> (K)) & 1u) {                                 \
        const float y0 = (P).x * LOG2E, y1 = (P).y * LOG2E;                    \
        const float y2 = (P).z * LOG2E, y3 = (P).w * LOG2E;                    \
        const float mx = fmaxf(fmaxf(y0, y1), fmaxf(y2, y3));                  \
        const unsigned long long mk = __ballot(mx > thr);                      \
        const int pos = cnt + __popcll(mk & ((1ull << lane) - 1ull));          \
        if (mx > thr && pos < TCAP) {                                          \
            tup[w][pos] = make_float4(y0, y1, y2, y3);                         \
            tub[w][pos] = (S) * 1024 + t * 4;                                  \
        }                                                                      \
        cnt += __popcll(mk);                                                   \
        if (cnt > TGUARD) { ovf = true; thr = FLT_MAX; }                       \
    }

    #pragma unroll 1
    for (int b = 0; b < NB8; ++b) {
        const int s = b * 8;
        const float4 X0 = seg4[(s + 0) * 256 + t];
        const float4 X1 = seg4[(s + 1) * 256 + t];
        const float4 X2 = seg4[(s + 2) * 256 + t];
        const float4 X3 = seg4[(s + 3) * 256 + t];
        const float4 X4 = seg4[(s + 4) * 256 + t];
        const float4 X5 = seg4[(s + 5) * 256 + t];
        const float4 X6 = seg4[(s + 6) * 256 + t];
        const float4 X7 = seg4[(s + 7) * 256 + t];

        unsigned fl = 0;
        PSTEP(0, X0); PSTEP(1, X1); PSTEP(2, X2); PSTEP(3, X3);
        PSTEP(4, X4); PSTEP(5, X5); PSTEP(6, X6); PSTEP(7, X7);

        if (fl) {                              // one cold-ish branch per batch
            ASTEP(0, X0, s + 0) ASTEP(1, X1, s + 1)
            ASTEP(2, X2, s + 2) ASTEP(3, X3, s + 3)
            ASTEP(4, X4, s + 4) ASTEP(5, X5, s + 5)
            ASTEP(6, X6, s + 6) ASTEP(7, X7, s + 7)
        }
    }
    // tail: steps 120..124 (same pattern, batch of 5)
    {
        const float4 X0 = seg4[120 * 256 + t];
        const float4 X1 = seg4[121 * 256 + t];
        const float4 X2 = seg4[122 * 256 + t];
        const float4 X3 = seg4[123 * 256 + t];
        const float4 X4 = seg4[124 * 256 + t];
        unsigned fl = 0;
        PSTEP(0, X0); PSTEP(1, X1); PSTEP(2, X2); PSTEP(3, X3); PSTEP(4, X4);
        if (fl) {
            ASTEP(0, X0, 120) ASTEP(1, X1, 121) ASTEP(2, X2, 122)
            ASTEP(3, X3, 123) ASTEP(4, X4, 124)
        }
    }
#undef PSTEP
#undef ASTEP

    // ---- cold region from here ----

    float kv = -FLT_MAX; int ki = 0;
    auto do_flush = [&](int n) {
        kv = -FLT_MAX; ki = 0;
        for (int r = 0; r < KTOP; r++) {
            float bv = -FLT_MAX; int bi = INT_MAX; int bp = -1;
            for (int e = lane; e < n; e += 64) {
                const float v  = rbv[e];
                const int   ii = rbi[e];
                if (v > bv || (v == bv && ii < bi)) { bv = v; bi = ii; bp = e; }
            }
            for (int o = 32; o > 0; o >>= 1) {
                const float ov = __shfl_xor(bv, o);
                const int   oi = __shfl_xor(bi, o);
                const int   op = __shfl_xor(bp, o);
                if (ov > bv || (ov == bv && oi < bi)) { bv = ov; bi = oi; bp = op; }
            }
            if (lane == 0 && bp >= 0) rbv[bp] = -FLT_MAX;   // consume
            if (lane == r) { kv = bv; ki = bi; }
            thr = bv;
        }
    };

    // expand tuples in place; count elems above static THRY
    const int nt = (cnt < TCAP) ? cnt : TCAP;
    int above = 0;
    for (int e = lane; e < nt; e += 64) {
        const float4 v = tup[w][e];
        const int    b = tub[w][e];
        above += (v.x > THRY) + (v.y > THRY) + (v.z > THRY) + (v.w > THRY);
        rbv[4 * e + 0] = v.x; rbi[4 * e + 0] = b + 0;
        rbv[4 * e + 1] = v.y; rbi[4 * e + 1] = b + 1;
        rbv[4 * e + 2] = v.z; rbi[4 * e + 2] = b + 2;
        rbv[4 * e + 3] = v.w; rbi[4 * e + 3] = b + 3;
    }
    for (int o = 32; o > 0; o >>= 1) above += __shfl_xor(above, o);

    // block reductions: sum + validity count
    float s = (s0 + s1) + (s2 + s3);
    for (int o = 32; o > 0; o >>= 1) s += __shfl_xor(s, o);
    if (lane == 0) { redS[w] = s; redC[w] = ovf ? -(1 << 20) : above; }
    __syncthreads();
    if (t == 0) wsS[row] = (redS[0] + redS[1]) + (redS[2] + redS[3]);
    const int blockcnt = redC[0] + redC[1] + redC[2] + redC[3];

    int cnt4 = 4 * nt;
    if (blockcnt < KTOP) {
        // cold exact rescue: rescan this wave's subset with self-raising thr
        thr = -FLT_MAX; cnt4 = 0;
        #pragma unroll 1
        for (int i = 0; i < NSTEP; ++i) {
            const float4 X = seg4[i * 256 + t];
            const float ys[4] = {X.x * LOG2E, X.y * LOG2E, X.z * LOG2E, X.w * LOG2E};
            #pragma unroll
            for (int j = 0; j < 4; ++j) {
                const bool pr = ys[j] > thr;
                const unsigned long long mk = __ballot(pr);
                if (mk) {
                    const int pos = cnt4 + __popcll(mk & ((1ull << lane) - 1ull));
                    if (pr && pos < RCAP) { rbv[pos] = ys[j]; rbi[pos] = i * 1024 + t * 4 + j; }
                    cnt4 += __popcll(mk);
                    if (cnt4 > RFLUSH) {
                        do_flush(cnt4);
                        if (lane < KTOP) { rbv[lane] = kv; rbi[lane] = ki; }
                        cnt4 = KTOP;
                    }
                }
            }
        }
    }

    do_flush(cnt4);   // final exact wave top-16 (pads -FLT_MAX if cnt4 < 16)

    // layout: 64 slots/row: row*64 + w*16 + r
    if (lane < KTOP) {
        wsV[(size_t)row * 64 + w * KTOP + lane] = kv;
        wsI[(size_t)row * 64 + w * KTOP + lane] = ki;
    }
}

// ---------------------------------------------------------------------------
// Kernel 2: one wave per batch. 16 rows x 64 candidates = 1024 candidates
// (16 per lane). Score sc = ln2*(y - log2(S)) + bs; top-16 with jax
// tie-break (score desc, flat idx rw*V+idx asc); f32 out.
// ---------------------------------------------------------------------------
__global__ __launch_bounds__(64) void k2_select(const float* __restrict__ wsS,
                                                const float* __restrict__ wsV,
                                                const int* __restrict__ wsI,
                                                const float* __restrict__ beam_scores,
                                                const int* __restrict__ dec_ids,
                                                const int* __restrict__ beam_idx_offset,
                                                float* __restrict__ out) {
    const int batch = blockIdx.x;
    const int lane  = threadIdx.x;   // 0..63

    __shared__ float LSs[NBEAMS], BSs[NBEAMS];
    if (lane < NBEAMS) {
        const int row = batch * NBEAMS + lane;
        LSs[lane] = log2f(wsS[row]);
        BSs[lane] = beam_scores[row];
    }
    __syncthreads();

    // candidate (p, lane): row p within batch, slot lane
    float sc[16]; int cb[16];
    #pragma unroll
    for (int p = 0; p < 16; p++) {
        const size_t base = (size_t)(batch * NBEAMS + p) * 64 + lane;
        const float v = wsV[base];               // y-domain (-FLT_MAX pads)
        const int idx = wsI[base];
        sc[p] = (v - LSs[p]) * LN2 + BSs[p];
        cb[p] = p * VOCABSZ + idx;
    }

    unsigned int selmask = 0;
    float fs = 0.f; int fc = 0;       // lane r keeps r-th winner
    for (int r = 0; r < KTOP; r++) {
        float bv = -FLT_MAX; int bi = INT_MAX; int bslot = -1;
        #pragma unroll
        for (int p = 0; p < 16; p++) {
            const bool avail = !((selmask >> p) & 1u);
            if (avail && (sc[p] > bv || (sc[p] == bv && cb[p] < bi))) {
                bv = sc[p]; bi = cb[p]; bslot = p;
            }
        }
        int bl = lane;
        for (int o = 32; o > 0; o >>= 1) {
            const float ov  = __shfl_xor(bv, o);
            const int   oi  = __shfl_xor(bi, o);
            const int   obl = __shfl_xor(bl, o);
            const int   obs = __shfl_xor(bslot, o);
            if (ov > bv || (ov == bv && oi < bi)) { bv = ov; bi = oi; bl = obl; bslot = obs; }
        }
        if (lane == bl) selmask |= (1u << bslot);
        if (lane == r) { fs = bv; fc = bi; }
    }

    if (lane < NBEAMS) {
        const int out_row = batch * NBEAMS + lane;
        const int beam  = fc / VOCABSZ;
        const int token = fc - beam * VOCABSZ;
        float* out0 = out;                          // (1024, 9) ids as f32
        float* out1 = out + ROWS * (CURLEN + 1);    // (1024,) scores
        out1[out_row] = fs;
        const int src = beam + beam_idx_offset[out_row];
        #pragma unroll
        for (int j = 0; j < CURLEN; j++)
            out0[out_row * (CURLEN + 1) + j] = (float)dec_ids[src * CURLEN + j];
        out0[out_row * (CURLEN + 1) + CURLEN] = (float)token;
    }
}

extern "C" void kernel_launch(void* const* d_in, const int* in_sizes, int n_in,
                              void* d_out, int out_size, void* d_ws, size_t ws_size,
                              hipStream_t stream) {
    const float* logits = (const float*)d_in[0];
    const int*   dec    = (const int*)d_in[1];
    const float* bscore = (const float*)d_in[2];
    const int*   bio    = (const int*)d_in[3];

    float* ws  = (float*)d_ws;
    float* wsS = ws;                       // 1024
    float* wsV = ws + ROWS;                // 1024*64
    int*   wsI = (int*)(ws + ROWS + ROWS * 64);

    k1_scan<<<ROWS, 256, 0, stream>>>(logits, wsS, wsV, wsI);
    k2_select<<<NBATCH, 64, 0, stream>>>(wsS, wsV, wsI, bscore, dec, bio,
                                         (float*)d_out);
}

// Round 15
// 121.071 us; speedup vs baseline: 3.0593x; 1.1331x over previous
//
#include <hip/hip_runtime.h>
#include <cfloat>
#include <climits>

#define ROWS    1024
#define VOCABSZ 128000
#define NBEAMS  16
#define NBATCH  64
#define CURLEN  8
#define KTOP    16
#define WPB     4                    // waves per block (kernel 1)
#define NSTEP   125                  // 125 float4-steps x 1024 floats = 128000
#define TCAP    96                   // tuple slots per wave (float4 + base)
#define TGUARD  80                   // stop appending past this (ovf -> rescue)
#define RCAP    (4 * TCAP)           // rescue/expand per-element capacity (384)
#define RFLUSH  320                  // rescue mid-flush threshold
#define LOG2E   1.4426950408889634f
#define LN2     0.6931471805599453f
#define THRY    (3.30f * LOG2E)      // static threshold, y-domain (~62/row)

#if __has_builtin(__builtin_amdgcn_exp2f)
#define EXP2(x) __builtin_amdgcn_exp2f(x)
#else
#define EXP2(x) exp2f(x)
#endif

typedef float fvec4 __attribute__((ext_vector_type(4)));

// ---------------------------------------------------------------------------
// Kernel 1: one block per row, 4 waves, grid 1024 (R10 geometry). Hot loop =
// R14's {8 pure steps + one deferred append branch} PLUS two load-path levers:
//  (1) batch-level double-buffer lookahead: loads for batch b+1 issue BEFORE
//      computing batch b (8-16 loads in flight per wave, no per-batch drain,
//      kills the convoy effect of issue->consume-immediately);
//  (2) nontemporal loads: stream hint, no cache allocation (data is
//      read-once per pass; mixed L3 residency gave ~700cy latencies).
// All top-k machinery is cold code after the loop (R10/R14 structure).
// Correctness for ANY input: wave ovf or row above-count<16 -> exact rescan.
// ---------------------------------------------------------------------------
__global__ __launch_bounds__(256) void k1_scan(const float* __restrict__ logits,
                                               float* __restrict__ wsS,
                                               float* __restrict__ wsV,
                                               int* __restrict__ wsI) {
    __shared__ float4 tup[WPB][TCAP];      // 6 KB  (aliased by rescue values)
    __shared__ int    tub[WPB][TCAP];      // 1.5 KB
    __shared__ int    rbix[WPB][RCAP];     // 6 KB  rescue indices
    __shared__ float  redS[WPB];
    __shared__ int    redC[WPB];

    const int row  = blockIdx.x;
    const int t    = threadIdx.x;          // 0..255
    const int w    = t >> 6;
    const int lane = t & 63;
    const fvec4* seg4 = reinterpret_cast<const fvec4*>(logits + (size_t)row * VOCABSZ);
    float* rbv = reinterpret_cast<float*>(&tup[w][0]);   // in-place expansion
    int*   rbi = &rbix[w][0];

    float s0 = 0.f, s1 = 0.f, s2 = 0.f, s3 = 0.f;
    float thr = THRY;
    int   cnt = 0;                   // wave-uniform tuple count
    bool  ovf = false;

    // pure step: sums + flag bit only (no memory ops)
#define PSTEP(K, P) do {                                                       \
        const float y0 = (P).x * LOG2E, y1 = (P).y * LOG2E;                    \
        const float y2 = (P).z * LOG2E, y3 = (P).w * LOG2E;                    \
        s0 += EXP2(y0); s1 += EXP2(y1); s2 += EXP2(y2); s3 += EXP2(y3);        \
        const float mx = fmaxf(fmaxf(y0, y1), fmaxf(y2, y3));                  \
        if (__any(mx > thr)) fl |= (1u << (K));                                \
    } while (0)

    // deferred append for flagged step (uses live X register; recompute y)
#define ASTEP(K, P, S) if ((fl >> (K)) & 1u) {                                 \
        const float y0 = (P).x * LOG2E, y1 = (P).y * LOG2E;                    \
        const float y2 = (P).z * LOG2E, y3 = (P).w * LOG2E;                    \
        const float mx = fmaxf(fmaxf(y0, y1), fmaxf(y2, y3));                  \
        const unsigned long long mk = __ballot(mx > thr);                      \
        const int pos = cnt + __popcll(mk & ((1ull << lane) - 1ull));          \
        if (mx > thr && pos < TCAP) {                                          \
            tup[w][pos] = make_float4(y0, y1, y2, y3);                         \
            tub[w][pos] = (S) * 1024 + t * 4;                                  \
        }                                                                      \
        cnt += __popcll(mk);                                                   \
        if (cnt > TGUARD) { ovf = true; thr = FLT_MAX; }                       \
    }

    // compute one 8-step batch held in named regs R0..R7, step base SB
#define CBATCH(R0,R1,R2,R3,R4,R5,R6,R7, SB) do {                               \
        unsigned fl = 0;                                                       \
        PSTEP(0, R0); PSTEP(1, R1); PSTEP(2, R2); PSTEP(3, R3);                \
        PSTEP(4, R4); PSTEP(5, R5); PSTEP(6, R6); PSTEP(7, R7);                \
        if (fl) {                                                              \
            ASTEP(0, R0, (SB)+0) ASTEP(1, R1, (SB)+1)                          \
            ASTEP(2, R2, (SB)+2) ASTEP(3, R3, (SB)+3)                          \
            ASTEP(4, R4, (SB)+4) ASTEP(5, R5, (SB)+5)                          \
            ASTEP(6, R6, (SB)+6) ASTEP(7, R7, (SB)+7)                          \
        }                                                                      \
    } while (0)

#define LD8(R0,R1,R2,R3,R4,R5,R6,R7, B) do {                                   \
        R0 = __builtin_nontemporal_load(&seg4[((B)*8+0)*256 + t]);             \
        R1 = __builtin_nontemporal_load(&seg4[((B)*8+1)*256 + t]);             \
        R2 = __builtin_nontemporal_load(&seg4[((B)*8+2)*256 + t]);             \
        R3 = __builtin_nontemporal_load(&seg4[((B)*8+3)*256 + t]);             \
        R4 = __builtin_nontemporal_load(&seg4[((B)*8+4)*256 + t]);             \
        R5 = __builtin_nontemporal_load(&seg4[((B)*8+5)*256 + t]);             \
        R6 = __builtin_nontemporal_load(&seg4[((B)*8+6)*256 + t]);             \
        R7 = __builtin_nontemporal_load(&seg4[((B)*8+7)*256 + t]);             \
    } while (0)

    fvec4 A0, A1, A2, A3, A4, A5, A6, A7;
    fvec4 B0, B1, B2, B3, B4, B5, B6, B7;

    // preload batch 0 into A; 15 full batches (steps 0..119), computed with
    // one-batch lookahead; unroll-by-2 keeps buffer selection static.
    LD8(A0,A1,A2,A3,A4,A5,A6,A7, 0);
    #pragma unroll 1
    for (int bb = 0; bb < 7; ++bb) {
        const int b = 2 * bb;
        LD8(B0,B1,B2,B3,B4,B5,B6,B7, b + 1);
        CBATCH(A0,A1,A2,A3,A4,A5,A6,A7, b * 8);
        LD8(A0,A1,A2,A3,A4,A5,A6,A7, b + 2);
        CBATCH(B0,B1,B2,B3,B4,B5,B6,B7, (b + 1) * 8);
    }
    CBATCH(A0,A1,A2,A3,A4,A5,A6,A7, 14 * 8);
    // tail: steps 120..124 (batch of 5, regular loads)
    {
        const fvec4 X0 = seg4[120 * 256 + t];
        const fvec4 X1 = seg4[121 * 256 + t];
        const fvec4 X2 = seg4[122 * 256 + t];
        const fvec4 X3 = seg4[123 * 256 + t];
        const fvec4 X4 = seg4[124 * 256 + t];
        unsigned fl = 0;
        PSTEP(0, X0); PSTEP(1, X1); PSTEP(2, X2); PSTEP(3, X3); PSTEP(4, X4);
        if (fl) {
            ASTEP(0, X0, 120) ASTEP(1, X1, 121) ASTEP(2, X2, 122)
            ASTEP(3, X3, 123) ASTEP(4, X4, 124)
        }
    }
#undef PSTEP
#undef ASTEP
#undef CBATCH
#undef LD8

    // ---- cold region from here ----

    float kv = -FLT_MAX; int ki = 0;
    auto do_flush = [&](int n) {
        kv = -FLT_MAX; ki = 0;
        for (int r = 0; r < KTOP; r++) {
            float bv = -FLT_MAX; int bi = INT_MAX; int bp = -1;
            for (int e = lane; e < n; e += 64) {
                const float v  = rbv[e];
                const int   ii = rbi[e];
                if (v > bv || (v == bv && ii < bi)) { bv = v; bi = ii; bp = e; }
            }
            for (int o = 32; o > 0; o >>= 1) {
                const float ov = __shfl_xor(bv, o);
                const int   oi = __shfl_xor(bi, o);
                const int   op = __shfl_xor(bp, o);
                if (ov > bv || (ov == bv && oi < bi)) { bv = ov; bi = oi; bp = op; }
            }
            if (lane == 0 && bp >= 0) rbv[bp] = -FLT_MAX;   // consume
            if (lane == r) { kv = bv; ki = bi; }
            thr = bv;
        }
    };

    // expand tuples in place; count elems above static THRY
    const int nt = (cnt < TCAP) ? cnt : TCAP;
    int above = 0;
    for (int e = lane; e < nt; e += 64) {
        const float4 v = tup[w][e];
        const int    b = tub[w][e];
        above += (v.x > THRY) + (v.y > THRY) + (v.z > THRY) + (v.w > THRY);
        rbv[4 * e + 0] = v.x; rbi[4 * e + 0] = b + 0;
        rbv[4 * e + 1] = v.y; rbi[4 * e + 1] = b + 1;
        rbv[4 * e + 2] = v.z; rbi[4 * e + 2] = b + 2;
        rbv[4 * e + 3] = v.w; rbi[4 * e + 3] = b + 3;
    }
    for (int o = 32; o > 0; o >>= 1) above += __shfl_xor(above, o);

    // block reductions: sum + validity count
    float s = (s0 + s1) + (s2 + s3);
    for (int o = 32; o > 0; o >>= 1) s += __shfl_xor(s, o);
    if (lane == 0) { redS[w] = s; redC[w] = ovf ? -(1 << 20) : above; }
    __syncthreads();
    if (t == 0) wsS[row] = (redS[0] + redS[1]) + (redS[2] + redS[3]);
    const int blockcnt = redC[0] + redC[1] + redC[2] + redC[3];

    int cnt4 = 4 * nt;
    if (blockcnt < KTOP) {
        // cold exact rescue: rescan this wave's subset with self-raising thr
        thr = -FLT_MAX; cnt4 = 0;
        #pragma unroll 1
        for (int i = 0; i < NSTEP; ++i) {
            const fvec4 X = seg4[i * 256 + t];
            const float ys[4] = {X.x * LOG2E, X.y * LOG2E, X.z * LOG2E, X.w * LOG2E};
            #pragma unroll
            for (int j = 0; j < 4; ++j) {
                const bool pr = ys[j] > thr;
                const unsigned long long mk = __ballot(pr);
                if (mk) {
                    const int pos = cnt4 + __popcll(mk & ((1ull << lane) - 1ull));
                    if (pr && pos < RCAP) { rbv[pos] = ys[j]; rbi[pos] = i * 1024 + t * 4 + j; }
                    cnt4 += __popcll(mk);
                    if (cnt4 > RFLUSH) {
                        do_flush(cnt4);
                        if (lane < KTOP) { rbv[lane] = kv; rbi[lane] = ki; }
                        cnt4 = KTOP;
                    }
                }
            }
        }
    }

    do_flush(cnt4);   // final exact wave top-16 (pads -FLT_MAX if cnt4 < 16)

    // layout: 64 slots/row: row*64 + w*16 + r
    if (lane < KTOP) {
        wsV[(size_t)row * 64 + w * KTOP + lane] = kv;
        wsI[(size_t)row * 64 + w * KTOP + lane] = ki;
    }
}

// ---------------------------------------------------------------------------
// Kernel 2: one wave per batch. 16 rows x 64 candidates = 1024 candidates
// (16 per lane). Score sc = ln2*(y - log2(S)) + bs; top-16 with jax
// tie-break (score desc, flat idx rw*V+idx asc); f32 out.
// ---------------------------------------------------------------------------
__global__ __launch_bounds__(64) void k2_select(const float* __restrict__ wsS,
                                                const float* __restrict__ wsV,
                                                const int* __restrict__ wsI,
                                                const float* __restrict__ beam_scores,
                                                const int* __restrict__ dec_ids,
                                                const int* __restrict__ beam_idx_offset,
                                                float* __restrict__ out) {
    const int batch = blockIdx.x;
    const int lane  = threadIdx.x;   // 0..63

    __shared__ float LSs[NBEAMS], BSs[NBEAMS];
    if (lane < NBEAMS) {
        const int row = batch * NBEAMS + lane;
        LSs[lane] = log2f(wsS[row]);
        BSs[lane] = beam_scores[row];
    }
    __syncthreads();

    // candidate (p, lane): row p within batch, slot lane
    float sc[16]; int cb[16];
    #pragma unroll
    for (int p = 0; p < 16; p++) {
        const size_t base = (size_t)(batch * NBEAMS + p) * 64 + lane;
        const float v = wsV[base];               // y-domain (-FLT_MAX pads)
        const int idx = wsI[base];
        sc[p] = (v - LSs[p]) * LN2 + BSs[p];
        cb[p] = p * VOCABSZ + idx;
    }

    unsigned int selmask = 0;
    float fs = 0.f; int fc = 0;       // lane r keeps r-th winner
    for (int r = 0; r < KTOP; r++) {
        float bv = -FLT_MAX; int bi = INT_MAX; int bslot = -1;
        #pragma unroll
        for (int p = 0; p < 16; p++) {
            const bool avail = !((selmask >> p) & 1u);
            if (avail && (sc[p] > bv || (sc[p] == bv && cb[p] < bi))) {
                bv = sc[p]; bi = cb[p]; bslot = p;
            }
        }
        int bl = lane;
        for (int o = 32; o > 0; o >>= 1) {
            const float ov  = __shfl_xor(bv, o);
            const int   oi  = __shfl_xor(bi, o);
            const int   obl = __shfl_xor(bl, o);
            const int   obs = __shfl_xor(bslot, o);
            if (ov > bv || (ov == bv && oi < bi)) { bv = ov; bi = oi; bl = obl; bslot = obs; }
        }
        if (lane == bl) selmask |= (1u << bslot);
        if (lane == r) { fs = bv; fc = bi; }
    }

    if (lane < NBEAMS) {
        const int out_row = batch * NBEAMS + lane;
        const int beam  = fc / VOCABSZ;
        const int token = fc - beam * VOCABSZ;
        float* out0 = out;                          // (1024, 9) ids as f32
        float* out1 = out + ROWS * (CURLEN + 1);    // (1024,) scores
        out1[out_row] = fs;
        const int src = beam + beam_idx_offset[out_row];
        #pragma unroll
        for (int j = 0; j < CURLEN; j++)
            out0[out_row * (CURLEN + 1) + j] = (float)dec_ids[src * CURLEN + j];
        out0[out_row * (CURLEN + 1) + CURLEN] = (float)token;
    }
}

extern "C" void kernel_launch(void* const* d_in, const int* in_sizes, int n_in,
                              void* d_out, int out_size, void* d_ws, size_t ws_size,
                              hipStream_t stream) {
    const float* logits = (const float*)d_in[0];
    const int*   dec    = (const int*)d_in[1];
    const float* bscore = (const float*)d_in[2];
    const int*   bio    = (const int*)d_in[3];

    float* ws  = (float*)d_ws;
    float* wsS = ws;                       // 1024
    float* wsV = ws + ROWS;                // 1024*64
    int*   wsI = (int*)(ws + ROWS + ROWS * 64);

    k1_scan<<<ROWS, 256, 0, stream>>>(logits, wsS, wsV, wsI);
    k2_select<<<NBATCH, 64, 0, stream>>>(wsS, wsV, wsI, bscore, dec, bio,
                                         (float*)d_out);
}